// Round 12
// baseline (7704.218 us; speedup 1.0000x reference)
//
#include <hip/hip_runtime.h>
#include <cstdint>

// ---------------------------------------------------------------------------
// 2-layer LSTM encoder, B=32 T=512 F=H=1024.
// Phase 1: pack x, W0, U0, [W1;U1] into bf16 MFMA-fragment order.
// Phase 2: big GEMM xz0 = x @ W0 (bf16, fp32 accum), GATE-INTERLEAVED output.
// Phase 3: persistent cooperative kernel, 256 WGs x 256 threads (4 waves),
//          R11 structure + SOFTWARE-PIPELINED minis: loads for mini k+1 are
//          issued during mini k's gates phase and stay in flight across RAW
//          s_barriers (counted vmcnt, T3/T4 mechanism). Wave2 polls for the
//          next mini during the load-wait window. Arithmetic identical R11.
// ---------------------------------------------------------------------------

typedef __attribute__((ext_vector_type(8))) short bf16x8;
typedef __attribute__((ext_vector_type(4))) short s16x4;
typedef __attribute__((ext_vector_type(4))) float f32x4;
typedef __attribute__((ext_vector_type(2))) unsigned int u32x2;

// workspace layout (bytes)
#define XZ0_OFF   0ull
#define XF_OFF    134217728ull
#define W0F_OFF   167772160ull
#define U0F_OFF   176160768ull
#define W1F_OFF   184549376ull
#define WS_TOTAL  201326592ull
#define RING_OFF  XF_OFF                 // 8 x 32x1024 bf16 = 524288
#define H1B_OFF   (XF_OFF + 524288ull)   // 2 x 32x1024 bf16 = 131072
#define FLG_OFF   (XF_OFF + 655360ull)   // 512 u32

__device__ __forceinline__ float bf2f(short s) {
  unsigned int u = ((unsigned int)(unsigned short)s) << 16;
  return __builtin_bit_cast(float, u);
}
__device__ __forceinline__ short f2bf(float f) {
  unsigned int u = __builtin_bit_cast(unsigned int, f);
  u = (u + 0x7fffu + ((u >> 16) & 1u)) >> 16;   // RTNE
  return (short)u;
}
__device__ __forceinline__ void g2l16(const void* g, void* l) {
  __builtin_amdgcn_global_load_lds(
      (const __attribute__((address_space(1))) unsigned int*)g,
      (__attribute__((address_space(3))) unsigned int*)l, 16, 0, 0);
}
__device__ __forceinline__ float sigm(float x) { return 1.f / (1.f + __expf(-x)); }

__device__ __forceinline__ bf16x8 ld16_sc1(const short* p) {
  bf16x8 r;
  asm volatile("global_load_dwordx4 %0, %1, off sc1" : "=&v"(r) : "v"(p));
  return r;
}
__device__ __forceinline__ s16x4 ld8_plain(const short* p) {
  s16x4 r;
  asm volatile("global_load_dwordx2 %0, %1, off" : "=&v"(r) : "v"(p));
  return r;
}
__device__ __forceinline__ void st2_sc1(short* p, unsigned v) {
  asm volatile("global_store_short %0, %1, off sc1" :: "v"(p), "v"(v) : "memory");
}
__device__ __forceinline__ void st4_sc1(unsigned* p, unsigned v) {
  asm volatile("global_store_dword %0, %1, off sc1" :: "v"(p), "v"(v) : "memory");
}
#define VM_DRAIN asm volatile("s_waitcnt vmcnt(0)" ::: "memory")
#define VM_W1    asm volatile("s_waitcnt vmcnt(1)" ::: "memory")
#define VM_W9    asm volatile("s_waitcnt vmcnt(9)" ::: "memory")
#define VM_W16   asm volatile("s_waitcnt vmcnt(16)" ::: "memory")
#define LGKM0    asm volatile("s_waitcnt lgkmcnt(0)" ::: "memory")
#define SBAR __builtin_amdgcn_sched_barrier(0)
#define RBAR __builtin_amdgcn_s_barrier()

// ---------------------------------------------------------------------------
__global__ __launch_bounds__(256) void pack_x(const float* __restrict__ x,
                                              short* __restrict__ dst) {
  int gid = blockIdx.x * 256 + threadIdx.x;
  int lane = gid & 63;
  int unit = gid >> 6;
  int mtile = unit >> 5, kstep = unit & 31;
  int row = mtile * 16 + (lane & 15);
  int k0 = kstep * 32 + ((lane >> 4) << 3);
  const float* s = x + (size_t)row * 1024 + k0;
  bf16x8 v;
#pragma unroll
  for (int j = 0; j < 8; j++) v[j] = f2bf(s[j]);
  *(bf16x8*)(dst + (size_t)gid * 8) = v;
}

// ---------------------------------------------------------------------------
__global__ __launch_bounds__(256) void pack_w(const float* __restrict__ src0,
                                              const float* __restrict__ src1,
                                              int ksh, short* __restrict__ dst) {
  int gid = blockIdx.x * 256 + threadIdx.x;
  int lane = gid & 63;
  int unit = gid >> 6;
  int ntile = unit >> ksh;
  int kstep = unit & ((1 << ksh) - 1);
  int col = ntile * 16 + (lane & 15);
  int k0 = kstep * 32 + ((lane >> 4) << 3);
  const float* s = (k0 < 1024) ? src0 : src1;
  int kk = k0 & 1023;
  bf16x8 v;
#pragma unroll
  for (int j = 0; j < 8; j++) v[j] = f2bf(s[(size_t)(kk + j) * 4096 + col]);
  *(bf16x8*)(dst + (size_t)gid * 8) = v;
}

// ---------------------------------------------------------------------------
// gemm_xw: xz0 = x @ W0, gate-interleaved epilogue [row][unit][gate]
// ---------------------------------------------------------------------------
__global__ __launch_bounds__(256) void gemm_xw(const short* __restrict__ xf,
                                               const short* __restrict__ wf,
                                               short* __restrict__ outz) {
  extern __shared__ char smem[];

  int bid = blockIdx.x;
  int swz = (bid & 7) * 512 + (bid >> 3);
  int bn = swz >> 7;
  int bm = swz & 127;

  const int tid = threadIdx.x, wid = tid >> 6, lane = tid & 63;
  const int wm = wid >> 1, wn = wid & 1;
  f32x4 acc[4][4] = {};

  const short* xbase = xf + (size_t)(bm * 8) * 32 * 512;
  const short* wbase = wf + (size_t)(bn * 8) * 32 * 512;

  auto Abuf = [&](int buf) -> short* { return (short*)(smem + buf * 32768); };
  auto Bbuf = [&](int buf) -> short* { return (short*)(smem + 16384 + buf * 32768); };

  auto stage = [&](int buf, int kt) {
    short* A = Abuf(buf);
    short* B = Bbuf(buf);
#pragma unroll
    for (int i = 0; i < 4; i++) {
      int u = wid + 4 * i;
      int mt = u >> 1, ks = u & 1;
      int gk = kt * 2 + ks;
      g2l16(xbase + (size_t)(mt * 32 + gk) * 512 + lane * 8, A + u * 512);
      g2l16(wbase + (size_t)(mt * 32 + gk) * 512 + lane * 8, B + u * 512);
    }
  };

  stage(0, 0);
  __syncthreads();
  for (int kt = 0; kt < 16; kt++) {
    int buf = kt & 1;
    if (kt < 15) stage(buf ^ 1, kt + 1);
    const short* A = Abuf(buf) + (wm * 4) * 1024;
    const short* B = Bbuf(buf) + (wn * 4) * 1024;
#pragma unroll
    for (int ks = 0; ks < 2; ks++) {
      bf16x8 av[4], bv[4];
#pragma unroll
      for (int i = 0; i < 4; i++) av[i] = *(const bf16x8*)(A + (i * 2 + ks) * 512 + lane * 8);
#pragma unroll
      for (int j = 0; j < 4; j++) bv[j] = *(const bf16x8*)(B + (j * 2 + ks) * 512 + lane * 8);
#pragma unroll
      for (int i = 0; i < 4; i++)
#pragma unroll
        for (int j = 0; j < 4; j++)
          acc[i][j] = __builtin_amdgcn_mfma_f32_16x16x32_bf16(av[i], bv[j], acc[i][j], 0, 0, 0);
    }
    __syncthreads();
  }

  int rb = bm * 128 + wm * 64 + ((lane >> 4) << 2);
  int cb = bn * 128 + wn * 64 + (lane & 15);
#pragma unroll
  for (int i = 0; i < 4; i++)
#pragma unroll
    for (int j = 0; j < 4; j++)
#pragma unroll
      for (int r = 0; r < 4; r++) {
        size_t row = rb + i * 16 + r;
        int col = cb + j * 16;
        outz[row * 4096 + (size_t)(col & 1023) * 4 + (col >> 10)] = f2bf(acc[i][j][r]);
      }
}

// ---------------------------------------------------------------------------
// lstm_persist: R11 + pipelined minis.
// flags: [0,128)=l0 g0, [128,256)=l0 g1, [256,384)=l1 g0, [384,512)=l1 g1
// ---------------------------------------------------------------------------
__global__ __launch_bounds__(256, 1) void lstm_persist(
    const short* __restrict__ xz0, const short* __restrict__ u0f,
    const short* __restrict__ w1u1f, const float* __restrict__ b0,
    const float* __restrict__ b1, short* __restrict__ h0ring,
    short* __restrict__ h1buf, unsigned int* __restrict__ flags,
    float* __restrict__ out) {
  extern __shared__ char smem[];
  short* wlds = (short*)smem;
  float* red0 = (float*)(smem + 131072);
  float* red1 = (float*)(smem + 139264);

  const int wg = blockIdx.x;
  const int tid = threadIdx.x;
  const int wid = tid >> 6;
  const int lane = tid & 63;
  const bool l1 = (wg >= 128);
  const int u0 = (wg & 127) * 8;
  const int KS = l1 ? 64 : 32;
  const int ksh = l1 ? 6 : 5;
  const short* wf = l1 ? w1u1f : u0f;

  // ---- LDS weight fill ----
  {
    int c = lane & 15;
    for (int u = wid; u < 2 * KS; u += 4) {
      int tau = u >> ksh;
      int s = u & (KS - 1);
      int gate = tau * 2 + (c >> 3);
      int gc = gate * 1024 + u0 + (c & 7);
      int lanep = (lane & 48) + (gc & 15);
      const short* src = wf + ((size_t)(((gc >> 4) << ksh) + s) * 64 + lanep) * 8;
      g2l16(src, wlds + (tau * KS + s) * 512);
    }
  }
  __syncthreads();

  const int bl = (tid & 127) >> 3;
  const int uu = tid & 7;
  const int lrow = bl >> 2, reg = bl & 3;
  float bias[4];
  {
    const float* bb = l1 ? b1 : b0;
#pragma unroll
    for (int g = 0; g < 4; g++) bias[g] = bb[g * 1024 + u0 + uu];
  }

  unsigned int* ownbase = flags + (l1 ? 256 : 0);
  unsigned int* othbase = flags + (l1 ? 0 : 256);

  auto pollq = [&](int q, unsigned own_t, unsigned oth_t) {
    if ((own_t | oth_t) == 0) return;
    const unsigned* po = ownbase + q * 128 + lane * 2;
    const unsigned* pe = othbase + q * 128 + lane * 2;
    for (int it = 0; it < (1 << 22); ++it) {
      u32x2 ov, ev;
      asm volatile(
          "global_load_dwordx2 %0, %2, off sc1\n\t"
          "global_load_dwordx2 %1, %3, off sc1\n\t"
          "s_waitcnt vmcnt(0)"
          : "=&v"(ov), "=&v"(ev)
          : "v"(po), "v"(pe)
          : "memory");
      if (__all(ov[0] >= own_t && ov[1] >= own_t &&
                ev[0] >= oth_t && ev[1] >= oth_t)) break;
      asm volatile("s_sleep 1");
    }
  };

  // gates for one group (tid<128); h-row = g*16+bl; issues ONE st2_sc1
  auto gates1 = [&](const float* rd, s16x4 xv, float& cst, short* hw,
                    bool dump, int g) {
    float z[4];
#pragma unroll
    for (int g4 = 0; g4 < 4; g4++) {
      int tau = g4 >> 1;
      int lp = lrow * 16 + (g4 & 1) * 8 + uu;
      float s = bias[g4] + bf2f(xv[g4]);
#pragma unroll
      for (int w4 = 0; w4 < 4; w4++)
        s += rd[((w4 * 2 + tau) * 64 + lp) * 4 + reg];
      z[g4] = s;
    }
    float gi = sigm(z[0]);
    float gf = sigm(z[1]);
    float gg = tanhf(z[2]);
    float go = sigm(z[3]);
    cst = gf * cst + gi * gg;
    float hv = go * tanhf(cst);
    if (dump) {
      int oi = (g * 16 + bl) * 1024 + u0 + uu;
      out[oi] = hv;
      out[32768 + oi] = hv;
      out[65536 + oi] = cst;
    }
    st2_sc1(hw + (g * 16 + bl) * 1024 + u0 + uu,
            (unsigned)(unsigned short)f2bf(hv));
  };

  if (!l1) {
    // ================= layer 0 =================
    bf16x8 A[8];
    s16x4 xv = {0, 0, 0, 0};
    auto issueA = [&](int g, int t) {
      const short* ap = h0ring + (size_t)((t - 1) & 7) * 32768 +
                        (g * 16 + (lane & 15)) * 1024 + (wid << 8) +
                        ((lane >> 4) << 3);
#pragma unroll
      for (int ks = 0; ks < 8; ks++) A[ks] = ld16_sc1(ap + ks * 32);
      if (tid < 128)
        xv = ld8_plain(xz0 +
             ((size_t)((g * 16 + bl) * 512 + t) * 1024 + u0 + uu) * 4);
    };
    auto body = [&](int g, int t, float& cst, int pq, unsigned po, unsigned pt,
                    bool donext, int ng, int nt, bool first) {
      if (wid == 2) pollq(pq, po, pt);      // poll for NEXT mini (vmcnt0 inside)
      if (first) { VM_DRAIN; }
      else if (wid == 0) { VM_W1; }         // leave own flag-store in flight
      else { VM_DRAIN; }
      SBAR;
      f32x4 acc0 = {}, acc1 = {};
#pragma unroll
      for (int ks = 0; ks < 8; ks++) {
        bf16x8 bt0 = *(const bf16x8*)(wlds + (wid * 8 + ks) * 512 + lane * 8);
        bf16x8 bt1 = *(const bf16x8*)(wlds + (32 + wid * 8 + ks) * 512 + lane * 8);
        acc0 = __builtin_amdgcn_mfma_f32_16x16x32_bf16(A[ks], bt0, acc0, 0, 0, 0);
        acc1 = __builtin_amdgcn_mfma_f32_16x16x32_bf16(A[ks], bt1, acc1, 0, 0, 0);
      }
      float* rd = g ? red1 : red0;
      *(f32x4*)(rd + ((wid * 2 + 0) * 64 + lane) * 4) = acc0;
      *(f32x4*)(rd + ((wid * 2 + 1) * 64 + lane) * 4) = acc1;
      LGKM0; RBAR; SBAR;                    // sync1: red visible
      s16x4 xcur = xv;
      if (tid < 128) {
        gates1(rd, xcur, cst, h0ring + (size_t)(t & 7) * 32768, false, g);
        if (donext) issueA(ng, nt);
      } else {
        if (donext) issueA(ng, nt);
      }
      if (donext) { VM_W9; } else { VM_DRAIN; }   // retire h-store, keep loads
      SBAR; RBAR;                           // sync2: all stores acked
      if (tid == 0)
        st4_sc1(ownbase + g * 128 + (wg & 127), (unsigned)(t + 1));
    };
    issueA(0, 0);
    float c0 = 0.f, c1 = 0.f;
    for (int t = 0; t < 512; ++t) {
      body(0, t, c0, 1, (unsigned)t, (t >= 8) ? (unsigned)(t - 7) : 0u,
           true, 1, t, t == 0);
      bool dn = (t < 511);
      body(1, t, c1, 0, dn ? (unsigned)(t + 1) : 0u,
           dn ? ((t + 1 >= 8) ? (unsigned)(t - 6) : 0u) : 0u,
           dn, 0, t + 1, false);
    }
  } else {
    // ================= layer 1 =================
    bf16x8 A1[2][8];
    auto issueA1 = [&](int g, int t) {
      const short* Ab = (wid < 2) ? (h0ring + (size_t)(t & 7) * 32768)
                                  : (h1buf + (size_t)((t - 1) & 1) * 32768);
      const short* ap = Ab + (g * 16 + (lane & 15)) * 1024 + ((wid & 1) << 9) +
                        ((lane >> 4) << 3);
#pragma unroll
      for (int half = 0; half < 2; half++)
#pragma unroll
        for (int ks = 0; ks < 8; ks++)
          A1[half][ks] = ld16_sc1(ap + half * 256 + ks * 32);
    };
    auto body = [&](int g, int t, float& cst, int pq, unsigned po, unsigned pt,
                    bool donext, int ng, int nt, bool first) {
      if (wid == 2) pollq(pq, po, pt);
      if (first) { VM_DRAIN; }
      else if (wid == 0) { VM_W1; }
      else { VM_DRAIN; }
      SBAR;
      f32x4 acc0 = {}, acc1 = {};
#pragma unroll
      for (int half = 0; half < 2; half++) {
        const int rb = wid * 16 + half * 8;
#pragma unroll
        for (int ks = 0; ks < 8; ks++) {
          bf16x8 bt0 = *(const bf16x8*)(wlds + (rb + ks) * 512 + lane * 8);
          bf16x8 bt1 = *(const bf16x8*)(wlds + (64 + rb + ks) * 512 + lane * 8);
          acc0 = __builtin_amdgcn_mfma_f32_16x16x32_bf16(A1[half][ks], bt0, acc0, 0, 0, 0);
          acc1 = __builtin_amdgcn_mfma_f32_16x16x32_bf16(A1[half][ks], bt1, acc1, 0, 0, 0);
        }
      }
      float* rd = g ? red1 : red0;
      *(f32x4*)(rd + ((wid * 2 + 0) * 64 + lane) * 4) = acc0;
      *(f32x4*)(rd + ((wid * 2 + 1) * 64 + lane) * 4) = acc1;
      LGKM0; RBAR; SBAR;                    // sync1
      if (tid < 128) {
        s16x4 zv = {0, 0, 0, 0};
        gates1(rd, zv, cst, h1buf + (size_t)(t & 1) * 32768, t == 511, g);
        if (donext) issueA1(ng, nt);
      } else {
        if (donext) issueA1(ng, nt);
      }
      if (donext) { VM_W16; } else { VM_DRAIN; }
      SBAR; RBAR;                           // sync2
      if (tid == 0)
        st4_sc1(ownbase + g * 128 + (wg & 127), (unsigned)(t + 1));
    };
    if (wid == 2) pollq(0, 0u, 1u);         // prologue: (g0,0) needs l0 g0 >= 1
    __syncthreads();
    issueA1(0, 0);
    float c0 = 0.f, c1 = 0.f;
    for (int t = 0; t < 512; ++t) {
      body(0, t, c0, 1, (unsigned)t, (unsigned)(t + 1), true, 1, t, t == 0);
      bool dn = (t < 511);
      body(1, t, c1, 0, dn ? (unsigned)(t + 1) : 0u,
           dn ? (unsigned)(t + 2) : 0u, dn, 0, t + 1, false);
    }
  }
}

// ---------------------------------------------------------------------------
extern "C" void kernel_launch(void* const* d_in, const int* in_sizes, int n_in,
                              void* d_out, int out_size, void* d_ws, size_t ws_size,
                              hipStream_t stream) {
  const float* x  = (const float*)d_in[0];
  const float* W0 = (const float*)d_in[1];
  const float* U0 = (const float*)d_in[2];
  const float* b0 = (const float*)d_in[3];
  const float* W1 = (const float*)d_in[4];
  const float* U1 = (const float*)d_in[5];
  const float* b1 = (const float*)d_in[6];
  char* ws = (char*)d_ws;
  if (ws_size < WS_TOTAL) return;

  short* xz0p = (short*)(ws + XZ0_OFF);
  short* xfp  = (short*)(ws + XF_OFF);
  short* w0fp = (short*)(ws + W0F_OFF);
  short* u0fp = (short*)(ws + U0F_OFF);
  short* w1fp = (short*)(ws + W1F_OFF);
  short* ringp = (short*)(ws + RING_OFF);
  short* h1p   = (short*)(ws + H1B_OFF);
  unsigned int* flagp = (unsigned int*)(ws + FLG_OFF);
  float* outp = (float*)d_out;

  (void)hipFuncSetAttribute((const void*)gemm_xw,
      hipFuncAttributeMaxDynamicSharedMemorySize, 65536);
  (void)hipFuncSetAttribute((const void*)lstm_persist,
      hipFuncAttributeMaxDynamicSharedMemorySize, 147456);

  hipLaunchKernelGGL(pack_x, dim3(8192), dim3(256), 0, stream, x, xfp);
  hipLaunchKernelGGL(pack_w, dim3(2048), dim3(256), 0, stream, W0, W0, 5, w0fp);
  hipLaunchKernelGGL(pack_w, dim3(2048), dim3(256), 0, stream, U0, U0, 5, u0fp);
  hipLaunchKernelGGL(pack_w, dim3(4096), dim3(256), 0, stream, W1, U1, 6, w1fp);
  hipLaunchKernelGGL(gemm_xw, dim3(4096), dim3(256), 65536, stream, xfp, w0fp, xz0p);

  (void)hipMemsetAsync(ws + RING_OFF, 0, 524288 + 131072 + 4096, stream);

  const short* xz0c = xz0p;
  const short* u0fc = u0fp;
  const short* w1fc = w1fp;
  void* kargs[9] = {(void*)&xz0c, (void*)&u0fc, (void*)&w1fc,
                    (void*)&b0,   (void*)&b1,
                    (void*)&ringp, (void*)&h1p, (void*)&flagp, (void*)&outp};
  (void)hipLaunchCooperativeKernel((const void*)lstm_persist, dim3(256), dim3(256),
                                   kargs, 147456u, stream);
}

// Round 13
// 5686.774 us; speedup vs baseline: 1.3548x; 1.3548x over previous
//
#include <hip/hip_runtime.h>
#include <cstdint>

// ---------------------------------------------------------------------------
// 2-layer LSTM encoder, B=32 T=512 F=H=1024.
// Phase 1: pack x, W0, U0, [W1;U1] into bf16 MFMA-fragment order.
// Phase 2: big GEMM xz0 = x @ W0 (bf16, fp32 accum), GATE-INTERLEAVED output.
// Phase 3: persistent cooperative kernel, 256 WGs x 256 threads (4 waves).
//          G=1: ONE 32-row mini per timestep per layer (half the rendezvous
//          of R11). Poll for step t+1 runs at END of step t AFTER the flag
//          release (release-before-poll -> no circular wait), overlapped
//          with the release ack on a different wave. Mechanics = R11:
//          sc1 LLC protocol, split-K over 4 waves, LDS reduce, 8-deep h0
//          ring, h1 double buffer. Per-row arithmetic identical to R11.
// ---------------------------------------------------------------------------

typedef __attribute__((ext_vector_type(8))) short bf16x8;
typedef __attribute__((ext_vector_type(4))) short s16x4;
typedef __attribute__((ext_vector_type(4))) float f32x4;
typedef __attribute__((ext_vector_type(2))) unsigned int u32x2;

// workspace layout (bytes)
#define XZ0_OFF   0ull
#define XF_OFF    134217728ull
#define W0F_OFF   167772160ull
#define U0F_OFF   176160768ull
#define W1F_OFF   184549376ull
#define WS_TOTAL  201326592ull
#define RING_OFF  XF_OFF                 // h0 ring: 8 x 32x1024 bf16 = 524288
#define H1B_OFF   (XF_OFF + 524288ull)   // h1 dbuf: 2 x 32x1024 bf16 = 131072
#define FLG_OFF   (XF_OFF + 655360ull)   // 256 u32: [l0 x128][l1 x128]

__device__ __forceinline__ float bf2f(short s) {
  unsigned int u = ((unsigned int)(unsigned short)s) << 16;
  return __builtin_bit_cast(float, u);
}
__device__ __forceinline__ short f2bf(float f) {
  unsigned int u = __builtin_bit_cast(unsigned int, f);
  u = (u + 0x7fffu + ((u >> 16) & 1u)) >> 16;   // RTNE
  return (short)u;
}
__device__ __forceinline__ void g2l16(const void* g, void* l) {
  __builtin_amdgcn_global_load_lds(
      (const __attribute__((address_space(1))) unsigned int*)g,
      (__attribute__((address_space(3))) unsigned int*)l, 16, 0, 0);
}
__device__ __forceinline__ float sigm(float x) { return 1.f / (1.f + __expf(-x)); }

__device__ __forceinline__ bf16x8 ld16_sc1(const short* p) {
  bf16x8 r;
  asm volatile("global_load_dwordx4 %0, %1, off sc1" : "=&v"(r) : "v"(p));
  return r;
}
__device__ __forceinline__ s16x4 ld8_plain(const short* p) {
  s16x4 r;
  asm volatile("global_load_dwordx2 %0, %1, off" : "=&v"(r) : "v"(p));
  return r;
}
__device__ __forceinline__ void st2_sc1(short* p, unsigned v) {
  asm volatile("global_store_short %0, %1, off sc1" :: "v"(p), "v"(v) : "memory");
}
__device__ __forceinline__ void st4_sc1(unsigned* p, unsigned v) {
  asm volatile("global_store_dword %0, %1, off sc1" :: "v"(p), "v"(v) : "memory");
}
#define VM_DRAIN asm volatile("s_waitcnt vmcnt(0)" ::: "memory")
#define VM_W16   asm volatile("s_waitcnt vmcnt(16)" ::: "memory")
#define SBAR __builtin_amdgcn_sched_barrier(0)

// 8 named fragments -> guaranteed VGPRs (rule 20)
struct Frag8 { bf16x8 f0, f1, f2, f3, f4, f5, f6, f7; };
#define LD8(F, B) do { \
  (F).f0 = ld16_sc1((B));       (F).f1 = ld16_sc1((B) + 32);  \
  (F).f2 = ld16_sc1((B) + 64);  (F).f3 = ld16_sc1((B) + 96);  \
  (F).f4 = ld16_sc1((B) + 128); (F).f5 = ld16_sc1((B) + 160); \
  (F).f6 = ld16_sc1((B) + 192); (F).f7 = ld16_sc1((B) + 224); \
} while (0)

// ---------------------------------------------------------------------------
__global__ __launch_bounds__(256) void pack_x(const float* __restrict__ x,
                                              short* __restrict__ dst) {
  int gid = blockIdx.x * 256 + threadIdx.x;
  int lane = gid & 63;
  int unit = gid >> 6;
  int mtile = unit >> 5, kstep = unit & 31;
  int row = mtile * 16 + (lane & 15);
  int k0 = kstep * 32 + ((lane >> 4) << 3);
  const float* s = x + (size_t)row * 1024 + k0;
  bf16x8 v;
#pragma unroll
  for (int j = 0; j < 8; j++) v[j] = f2bf(s[j]);
  *(bf16x8*)(dst + (size_t)gid * 8) = v;
}

// ---------------------------------------------------------------------------
__global__ __launch_bounds__(256) void pack_w(const float* __restrict__ src0,
                                              const float* __restrict__ src1,
                                              int ksh, short* __restrict__ dst) {
  int gid = blockIdx.x * 256 + threadIdx.x;
  int lane = gid & 63;
  int unit = gid >> 6;
  int ntile = unit >> ksh;
  int kstep = unit & ((1 << ksh) - 1);
  int col = ntile * 16 + (lane & 15);
  int k0 = kstep * 32 + ((lane >> 4) << 3);
  const float* s = (k0 < 1024) ? src0 : src1;
  int kk = k0 & 1023;
  bf16x8 v;
#pragma unroll
  for (int j = 0; j < 8; j++) v[j] = f2bf(s[(size_t)(kk + j) * 4096 + col]);
  *(bf16x8*)(dst + (size_t)gid * 8) = v;
}

// ---------------------------------------------------------------------------
// gemm_xw: xz0 = x @ W0, gate-interleaved epilogue [row][unit][gate]
// ---------------------------------------------------------------------------
__global__ __launch_bounds__(256) void gemm_xw(const short* __restrict__ xf,
                                               const short* __restrict__ wf,
                                               short* __restrict__ outz) {
  extern __shared__ char smem[];

  int bid = blockIdx.x;
  int swz = (bid & 7) * 512 + (bid >> 3);
  int bn = swz >> 7;
  int bm = swz & 127;

  const int tid = threadIdx.x, wid = tid >> 6, lane = tid & 63;
  const int wm = wid >> 1, wn = wid & 1;
  f32x4 acc[4][4] = {};

  const short* xbase = xf + (size_t)(bm * 8) * 32 * 512;
  const short* wbase = wf + (size_t)(bn * 8) * 32 * 512;

  auto Abuf = [&](int buf) -> short* { return (short*)(smem + buf * 32768); };
  auto Bbuf = [&](int buf) -> short* { return (short*)(smem + 16384 + buf * 32768); };

  auto stage = [&](int buf, int kt) {
    short* A = Abuf(buf);
    short* B = Bbuf(buf);
#pragma unroll
    for (int i = 0; i < 4; i++) {
      int u = wid + 4 * i;
      int mt = u >> 1, ks = u & 1;
      int gk = kt * 2 + ks;
      g2l16(xbase + (size_t)(mt * 32 + gk) * 512 + lane * 8, A + u * 512);
      g2l16(wbase + (size_t)(mt * 32 + gk) * 512 + lane * 8, B + u * 512);
    }
  };

  stage(0, 0);
  __syncthreads();
  for (int kt = 0; kt < 16; kt++) {
    int buf = kt & 1;
    if (kt < 15) stage(buf ^ 1, kt + 1);
    const short* A = Abuf(buf) + (wm * 4) * 1024;
    const short* B = Bbuf(buf) + (wn * 4) * 1024;
#pragma unroll
    for (int ks = 0; ks < 2; ks++) {
      bf16x8 av[4], bv[4];
#pragma unroll
      for (int i = 0; i < 4; i++) av[i] = *(const bf16x8*)(A + (i * 2 + ks) * 512 + lane * 8);
#pragma unroll
      for (int j = 0; j < 4; j++) bv[j] = *(const bf16x8*)(B + (j * 2 + ks) * 512 + lane * 8);
#pragma unroll
      for (int i = 0; i < 4; i++)
#pragma unroll
        for (int j = 0; j < 4; j++)
          acc[i][j] = __builtin_amdgcn_mfma_f32_16x16x32_bf16(av[i], bv[j], acc[i][j], 0, 0, 0);
    }
    __syncthreads();
  }

  int rb = bm * 128 + wm * 64 + ((lane >> 4) << 2);
  int cb = bn * 128 + wn * 64 + (lane & 15);
#pragma unroll
  for (int i = 0; i < 4; i++)
#pragma unroll
    for (int j = 0; j < 4; j++)
#pragma unroll
      for (int r = 0; r < 4; r++) {
        size_t row = rb + i * 16 + r;
        int col = cb + j * 16;
        outz[row * 4096 + (size_t)(col & 1023) * 4 + (col >> 10)] = f2bf(acc[i][j][r]);
      }
}

// ---------------------------------------------------------------------------
// lstm_persist: G=1, one 32-row mini per step.
// flags: [0,128) = l0 WGs, [128,256) = l1 WGs.
// ---------------------------------------------------------------------------
__global__ __launch_bounds__(256, 1) void lstm_persist(
    const short* __restrict__ xz0, const short* __restrict__ u0f,
    const short* __restrict__ w1u1f, const float* __restrict__ b0,
    const float* __restrict__ b1, short* __restrict__ h0ring,
    short* __restrict__ h1buf, unsigned int* __restrict__ flags,
    float* __restrict__ out) {
  extern __shared__ char smem[];
  short* wlds = (short*)smem;                 // weights: 64KB (l0) / 128KB (l1)
  float* red = (float*)(smem + 131072);       // 16KB: 16 slots x 64 lanes x f32x4

  const int wg = blockIdx.x;
  const int tid = threadIdx.x;
  const int wid = tid >> 6;
  const int lane = tid & 63;
  const bool l1 = (wg >= 128);
  const int u0 = (wg & 127) * 8;
  const int KS = l1 ? 64 : 32;
  const int ksh = l1 ? 6 : 5;
  const short* wf = l1 ? w1u1f : u0f;

  // ---- LDS weight fill (same gather as R11) ----
  {
    int c = lane & 15;
    for (int u = wid; u < 2 * KS; u += 4) {
      int tau = u >> ksh;
      int s = u & (KS - 1);
      int gate = tau * 2 + (c >> 3);
      int gc = gate * 1024 + u0 + (c & 7);
      int lanep = (lane & 48) + (gc & 15);
      const short* src = wf + ((size_t)(((gc >> 4) << ksh) + s) * 64 + lanep) * 8;
      g2l16(src, wlds + (tau * KS + s) * 512);
    }
  }
  __syncthreads();

  const int un = tid & 7;                     // gate unit (tid<128)
  const int r1 = (tid & 127) >> 3;            // gate row A (0..15, mt 0)
  const int r2 = r1 + 16;                     // gate row B (16..31, mt 1)
  float bias[4];
  {
    const float* bb = l1 ? b1 : b0;
#pragma unroll
    for (int g4 = 0; g4 < 4; g4++) bias[g4] = bb[g4 * 1024 + u0 + un];
  }
  float cA = 0.f, cB = 0.f;

  unsigned int* ownf = flags + (l1 ? 128 : 0);
  unsigned int* othf = flags + (l1 ? 0 : 128);

  // wave-wide poll over all 128 flags of each side (caller guards wave)
  auto pollq = [&](unsigned own_t, unsigned oth_t) {
    if ((own_t | oth_t) == 0) return;
    const unsigned* po = ownf + lane * 2;
    const unsigned* pe = othf + lane * 2;
    for (int it = 0; it < (1 << 22); ++it) {
      u32x2 ov, ev;
      asm volatile(
          "global_load_dwordx2 %0, %2, off sc1\n\t"
          "global_load_dwordx2 %1, %3, off sc1\n\t"
          "s_waitcnt vmcnt(0)"
          : "=&v"(ov), "=&v"(ev)
          : "v"(po), "v"(pe)
          : "memory");
      if (__all(ov[0] >= own_t && ov[1] >= own_t &&
                ev[0] >= oth_t && ev[1] >= oth_t)) break;
      asm volatile("s_sleep 1");
    }
  };

  // gates for one row r (mt = r>>4); updates cst, stores h, optional dump
  auto gaterow = [&](int r, s16x4 xv, float& cst, short* hw, bool dump) {
    const int mt = r >> 4, bl = r & 15;
    const int reg = bl & 3;
    float z[4];
#pragma unroll
    for (int g4 = 0; g4 < 4; g4++) {
      int tau = g4 >> 1;
      int lp = (bl >> 2) * 16 + (g4 & 1) * 8 + un;
      float s = bias[g4] + bf2f(xv[g4]);
#pragma unroll
      for (int w4 = 0; w4 < 4; w4++)
        s += red[((w4 * 4 + mt * 2 + tau) * 64 + lp) * 4 + reg];
      z[g4] = s;
    }
    float gi = sigm(z[0]);
    float gf = sigm(z[1]);
    float gg = tanhf(z[2]);
    float go = sigm(z[3]);
    cst = gf * cst + gi * gg;
    float hv = go * tanhf(cst);
    if (dump) {
      int oi = r * 1024 + u0 + un;
      out[oi] = hv;
      out[32768 + oi] = hv;
      out[65536 + oi] = cst;
    }
    st2_sc1(hw + r * 1024 + u0 + un, (unsigned)(unsigned short)f2bf(hv));
  };

  if (!l1) {
    // ================= layer 0: 512 steps, h0 ring depth 8 =================
    for (int t = 0; t < 512; ++t) {
      // A loads: both mtiles, this wave's 256-wide K slice (16 in flight)
      const short* ap = h0ring + (size_t)((t - 1) & 7) * 32768 +
                        (lane & 15) * 1024 + (wid << 8) + ((lane >> 4) << 3);
      Frag8 Fa, Fb;
      LD8(Fa, ap);            // mt 0 (rows 0..15)
      LD8(Fb, ap + 16384);    // mt 1 (rows 16..31)
      s16x4 xvA = {0, 0, 0, 0}, xvB = {0, 0, 0, 0};
      if (tid < 128) {
        xvA = ld8_plain(xz0 + ((size_t)(r1 * 512 + t) * 1024 + u0 + un) * 4);
        xvB = ld8_plain(xz0 + ((size_t)(r2 * 512 + t) * 1024 + u0 + un) * 4);
      }
      SBAR; VM_DRAIN; SBAR;
      f32x4 a00 = {}, a01 = {}, a10 = {}, a11 = {};   // [mt][tau]
#pragma unroll
      for (int ks = 0; ks < 8; ks++) {
        bf16x8 bt0 = *(const bf16x8*)(wlds + (wid * 8 + ks) * 512 + lane * 8);
        bf16x8 bt1 = *(const bf16x8*)(wlds + (32 + wid * 8 + ks) * 512 + lane * 8);
        bf16x8 fa = ks == 0 ? Fa.f0 : ks == 1 ? Fa.f1 : ks == 2 ? Fa.f2 :
                    ks == 3 ? Fa.f3 : ks == 4 ? Fa.f4 : ks == 5 ? Fa.f5 :
                    ks == 6 ? Fa.f6 : Fa.f7;
        bf16x8 fb = ks == 0 ? Fb.f0 : ks == 1 ? Fb.f1 : ks == 2 ? Fb.f2 :
                    ks == 3 ? Fb.f3 : ks == 4 ? Fb.f4 : ks == 5 ? Fb.f5 :
                    ks == 6 ? Fb.f6 : Fb.f7;
        a00 = __builtin_amdgcn_mfma_f32_16x16x32_bf16(fa, bt0, a00, 0, 0, 0);
        a01 = __builtin_amdgcn_mfma_f32_16x16x32_bf16(fa, bt1, a01, 0, 0, 0);
        a10 = __builtin_amdgcn_mfma_f32_16x16x32_bf16(fb, bt0, a10, 0, 0, 0);
        a11 = __builtin_amdgcn_mfma_f32_16x16x32_bf16(fb, bt1, a11, 0, 0, 0);
      }
      *(f32x4*)(red + ((wid * 4 + 0) * 64 + lane) * 4) = a00;
      *(f32x4*)(red + ((wid * 4 + 1) * 64 + lane) * 4) = a01;
      *(f32x4*)(red + ((wid * 4 + 2) * 64 + lane) * 4) = a10;
      *(f32x4*)(red + ((wid * 4 + 3) * 64 + lane) * 4) = a11;
      __syncthreads();                                 // sync1: red visible
      if (tid < 128) {
        short* hw = h0ring + (size_t)(t & 7) * 32768;
        gaterow(r1, xvA, cA, hw, false);
        gaterow(r2, xvB, cB, hw, false);
      }
      __syncthreads();                                 // sync2: h stores drained
      if (tid == 0) st4_sc1(ownf + (wg & 127), (unsigned)(t + 1));
      if (wid == 2 && t < 511)                         // poll for step t+1
        pollq((unsigned)(t + 1), (t + 1 >= 8) ? (unsigned)(t - 6) : 0u);
      __syncthreads();                                 // sync3
    }
  } else {
    // ================= layer 1: 512 steps, h0 ring + h1 dbuf ================
    if (wid == 2) pollq(0u, 1u);     // prologue: step 0 needs l0 >= 1
    __syncthreads();
    for (int t = 0; t < 512; ++t) {
      // A loads: waves 0,1 read h0(t); waves 2,3 read h1(t-1). 32 in flight.
      const short* Ab = (wid < 2) ? (h0ring + (size_t)(t & 7) * 32768)
                                  : (h1buf + (size_t)((t - 1) & 1) * 32768);
      const short* ap = Ab + (lane & 15) * 1024 + ((wid & 1) << 9) +
                        ((lane >> 4) << 3);
      Frag8 Fa, Fb, Fc, Fd;
      LD8(Fa, ap);                 // half 0, mt 0
      LD8(Fb, ap + 16384);         // half 0, mt 1
      LD8(Fc, ap + 256);           // half 1, mt 0
      LD8(Fd, ap + 256 + 16384);   // half 1, mt 1
      SBAR; VM_W16; SBAR;          // Fa,Fb done; Fc,Fd still flying
      f32x4 a00 = {}, a01 = {}, a10 = {}, a11 = {};
#pragma unroll
      for (int ks = 0; ks < 8; ks++) {
        bf16x8 bt0 = *(const bf16x8*)(wlds + (wid * 16 + ks) * 512 + lane * 8);
        bf16x8 bt1 = *(const bf16x8*)(wlds + (64 + wid * 16 + ks) * 512 + lane * 8);
        bf16x8 fa = ks == 0 ? Fa.f0 : ks == 1 ? Fa.f1 : ks == 2 ? Fa.f2 :
                    ks == 3 ? Fa.f3 : ks == 4 ? Fa.f4 : ks == 5 ? Fa.f5 :
                    ks == 6 ? Fa.f6 : Fa.f7;
        bf16x8 fb = ks == 0 ? Fb.f0 : ks == 1 ? Fb.f1 : ks == 2 ? Fb.f2 :
                    ks == 3 ? Fb.f3 : ks == 4 ? Fb.f4 : ks == 5 ? Fb.f5 :
                    ks == 6 ? Fb.f6 : Fb.f7;
        a00 = __builtin_amdgcn_mfma_f32_16x16x32_bf16(fa, bt0, a00, 0, 0, 0);
        a01 = __builtin_amdgcn_mfma_f32_16x16x32_bf16(fa, bt1, a01, 0, 0, 0);
        a10 = __builtin_amdgcn_mfma_f32_16x16x32_bf16(fb, bt0, a10, 0, 0, 0);
        a11 = __builtin_amdgcn_mfma_f32_16x16x32_bf16(fb, bt1, a11, 0, 0, 0);
      }
      SBAR; VM_DRAIN; SBAR;        // Fc,Fd done (RT hidden under half-0 MFMA)
#pragma unroll
      for (int ks = 0; ks < 8; ks++) {
        bf16x8 bt0 = *(const bf16x8*)(wlds + (wid * 16 + 8 + ks) * 512 + lane * 8);
        bf16x8 bt1 = *(const bf16x8*)(wlds + (64 + wid * 16 + 8 + ks) * 512 + lane * 8);
        bf16x8 fc = ks == 0 ? Fc.f0 : ks == 1 ? Fc.f1 : ks == 2 ? Fc.f2 :
                    ks == 3 ? Fc.f3 : ks == 4 ? Fc.f4 : ks == 5 ? Fc.f5 :
                    ks == 6 ? Fc.f6 : Fc.f7;
        bf16x8 fd = ks == 0 ? Fd.f0 : ks == 1 ? Fd.f1 : ks == 2 ? Fd.f2 :
                    ks == 3 ? Fd.f3 : ks == 4 ? Fd.f4 : ks == 5 ? Fd.f5 :
                    ks == 6 ? Fd.f6 : Fd.f7;
        a00 = __builtin_amdgcn_mfma_f32_16x16x32_bf16(fc, bt0, a00, 0, 0, 0);
        a01 = __builtin_amdgcn_mfma_f32_16x16x32_bf16(fc, bt1, a01, 0, 0, 0);
        a10 = __builtin_amdgcn_mfma_f32_16x16x32_bf16(fd, bt0, a10, 0, 0, 0);
        a11 = __builtin_amdgcn_mfma_f32_16x16x32_bf16(fd, bt1, a11, 0, 0, 0);
      }
      *(f32x4*)(red + ((wid * 4 + 0) * 64 + lane) * 4) = a00;
      *(f32x4*)(red + ((wid * 4 + 1) * 64 + lane) * 4) = a01;
      *(f32x4*)(red + ((wid * 4 + 2) * 64 + lane) * 4) = a10;
      *(f32x4*)(red + ((wid * 4 + 3) * 64 + lane) * 4) = a11;
      __syncthreads();                                 // sync1
      if (tid < 128) {
        short* hw = h1buf + (size_t)(t & 1) * 32768;
        s16x4 zv = {0, 0, 0, 0};
        gaterow(r1, zv, cA, hw, t == 511);
        gaterow(r2, zv, cB, hw, t == 511);
      }
      __syncthreads();                                 // sync2
      if (tid == 0) st4_sc1(ownf + (wg & 127), (unsigned)(t + 1));
      if (wid == 2 && t < 511)                         // poll for step t+1
        pollq((unsigned)(t + 1), (unsigned)(t + 2));
      __syncthreads();                                 // sync3
    }
  }
}

// ---------------------------------------------------------------------------
extern "C" void kernel_launch(void* const* d_in, const int* in_sizes, int n_in,
                              void* d_out, int out_size, void* d_ws, size_t ws_size,
                              hipStream_t stream) {
  const float* x  = (const float*)d_in[0];
  const float* W0 = (const float*)d_in[1];
  const float* U0 = (const float*)d_in[2];
  const float* b0 = (const float*)d_in[3];
  const float* W1 = (const float*)d_in[4];
  const float* U1 = (const float*)d_in[5];
  const float* b1 = (const float*)d_in[6];
  char* ws = (char*)d_ws;
  if (ws_size < WS_TOTAL) return;

  short* xz0p = (short*)(ws + XZ0_OFF);
  short* xfp  = (short*)(ws + XF_OFF);
  short* w0fp = (short*)(ws + W0F_OFF);
  short* u0fp = (short*)(ws + U0F_OFF);
  short* w1fp = (short*)(ws + W1F_OFF);
  short* ringp = (short*)(ws + RING_OFF);
  short* h1p   = (short*)(ws + H1B_OFF);
  unsigned int* flagp = (unsigned int*)(ws + FLG_OFF);
  float* outp = (float*)d_out;

  (void)hipFuncSetAttribute((const void*)gemm_xw,
      hipFuncAttributeMaxDynamicSharedMemorySize, 65536);
  (void)hipFuncSetAttribute((const void*)lstm_persist,
      hipFuncAttributeMaxDynamicSharedMemorySize, 147456);

  hipLaunchKernelGGL(pack_x, dim3(8192), dim3(256), 0, stream, x, xfp);
  hipLaunchKernelGGL(pack_w, dim3(2048), dim3(256), 0, stream, W0, W0, 5, w0fp);
  hipLaunchKernelGGL(pack_w, dim3(2048), dim3(256), 0, stream, U0, U0, 5, u0fp);
  hipLaunchKernelGGL(pack_w, dim3(4096), dim3(256), 0, stream, W1, U1, 6, w1fp);
  hipLaunchKernelGGL(gemm_xw, dim3(4096), dim3(256), 65536, stream, xfp, w0fp, xz0p);

  (void)hipMemsetAsync(ws + RING_OFF, 0, 524288 + 131072 + 4096, stream);

  const short* xz0c = xz0p;
  const short* u0fc = u0fp;
  const short* w1fc = w1fp;
  void* kargs[9] = {(void*)&xz0c, (void*)&u0fc, (void*)&w1fc,
                    (void*)&b0,   (void*)&b1,
                    (void*)&ringp, (void*)&h1p, (void*)&flagp, (void*)&outp};
  (void)hipLaunchCooperativeKernel((const void*)lstm_persist, dim3(256), dim3(256),
                                   kargs, 147456u, stream);
}

// Round 14
// 4868.386 us; speedup vs baseline: 1.5825x; 1.1681x over previous
//
#include <hip/hip_runtime.h>
#include <cstdint>

// ---------------------------------------------------------------------------
// 2-layer LSTM encoder, B=32 T=512 F=H=1024.
// Phase 1: pack x, W0, U0, [W1;U1] into bf16 MFMA-fragment order.
// Phase 2: big GEMM xz0 = x @ W0 (bf16, fp32 accum), GATE-INTERLEAVED output.
// Phase 3: persistent cooperative kernel, 256 WGs x 256 threads (4 waves).
//          G=2 interleaved chains (R11 structure) with WAVE-AUTONOMOUS
//          NARROW POLLS: each wave polls only its 32-64 producer WGs right
//          before its own loads; gates distributed over all 4 waves; per-wave
//          release flags (4 words/WG/group) -> ONE barrier per mini.
//          h0 and h1 both 8-deep rings; all cross-WG traffic sc1 @ LLC.
// ---------------------------------------------------------------------------

typedef __attribute__((ext_vector_type(8))) short bf16x8;
typedef __attribute__((ext_vector_type(4))) short s16x4;
typedef __attribute__((ext_vector_type(4))) float f32x4;
typedef __attribute__((ext_vector_type(2))) unsigned int u32x2;
typedef __attribute__((ext_vector_type(4))) unsigned int u32x4;

// workspace layout (bytes)
#define XZ0_OFF   0ull
#define XF_OFF    134217728ull
#define W0F_OFF   167772160ull
#define U0F_OFF   176160768ull
#define W1F_OFF   184549376ull
#define WS_TOTAL  201326592ull
#define H0R_OFF   XF_OFF                  // h0 ring: 8 x 32x1024 bf16 = 524288
#define H1R_OFF   (XF_OFF + 524288ull)    // h1 ring: 8 x 32x1024 bf16 = 524288
#define FLG_OFF   (XF_OFF + 1048576ull)   // u32[2][2][128][4] = 8192 B

__device__ __forceinline__ float bf2f(short s) {
  unsigned int u = ((unsigned int)(unsigned short)s) << 16;
  return __builtin_bit_cast(float, u);
}
__device__ __forceinline__ short f2bf(float f) {
  unsigned int u = __builtin_bit_cast(unsigned int, f);
  u = (u + 0x7fffu + ((u >> 16) & 1u)) >> 16;   // RTNE
  return (short)u;
}
__device__ __forceinline__ void g2l16(const void* g, void* l) {
  __builtin_amdgcn_global_load_lds(
      (const __attribute__((address_space(1))) unsigned int*)g,
      (__attribute__((address_space(3))) unsigned int*)l, 16, 0, 0);
}
__device__ __forceinline__ float sigm(float x) { return 1.f / (1.f + __expf(-x)); }

__device__ __forceinline__ bf16x8 ld16_sc1(const short* p) {
  bf16x8 r;
  asm volatile("global_load_dwordx4 %0, %1, off sc1" : "=&v"(r) : "v"(p));
  return r;
}
__device__ __forceinline__ s16x4 ld8_plain(const short* p) {
  s16x4 r;
  asm volatile("global_load_dwordx2 %0, %1, off" : "=&v"(r) : "v"(p));
  return r;
}
__device__ __forceinline__ void st2_sc1(short* p, unsigned v) {
  asm volatile("global_store_short %0, %1, off sc1" :: "v"(p), "v"(v) : "memory");
}
__device__ __forceinline__ void st4_sc1(unsigned* p, unsigned v) {
  asm volatile("global_store_dword %0, %1, off sc1" :: "v"(p), "v"(v) : "memory");
}
#define VM_DRAIN asm volatile("s_waitcnt vmcnt(0)" ::: "memory")
#define SBAR __builtin_amdgcn_sched_barrier(0)

// 8 named fragments -> guaranteed VGPRs (rule 20)
struct Frag8 { bf16x8 f0, f1, f2, f3, f4, f5, f6, f7; };
#define LD8(F, B) do { \
  (F).f0 = ld16_sc1((B));       (F).f1 = ld16_sc1((B) + 32);  \
  (F).f2 = ld16_sc1((B) + 64);  (F).f3 = ld16_sc1((B) + 96);  \
  (F).f4 = ld16_sc1((B) + 128); (F).f5 = ld16_sc1((B) + 160); \
  (F).f6 = ld16_sc1((B) + 192); (F).f7 = ld16_sc1((B) + 224); \
} while (0)
#define FSEL(F, ks) (ks == 0 ? (F).f0 : ks == 1 ? (F).f1 : ks == 2 ? (F).f2 : \
                     ks == 3 ? (F).f3 : ks == 4 ? (F).f4 : ks == 5 ? (F).f5 : \
                     ks == 6 ? (F).f6 : (F).f7)

// ---------------------------------------------------------------------------
__global__ __launch_bounds__(256) void pack_x(const float* __restrict__ x,
                                              short* __restrict__ dst) {
  int gid = blockIdx.x * 256 + threadIdx.x;
  int lane = gid & 63;
  int unit = gid >> 6;
  int mtile = unit >> 5, kstep = unit & 31;
  int row = mtile * 16 + (lane & 15);
  int k0 = kstep * 32 + ((lane >> 4) << 3);
  const float* s = x + (size_t)row * 1024 + k0;
  bf16x8 v;
#pragma unroll
  for (int j = 0; j < 8; j++) v[j] = f2bf(s[j]);
  *(bf16x8*)(dst + (size_t)gid * 8) = v;
}

// ---------------------------------------------------------------------------
__global__ __launch_bounds__(256) void pack_w(const float* __restrict__ src0,
                                              const float* __restrict__ src1,
                                              int ksh, short* __restrict__ dst) {
  int gid = blockIdx.x * 256 + threadIdx.x;
  int lane = gid & 63;
  int unit = gid >> 6;
  int ntile = unit >> ksh;
  int kstep = unit & ((1 << ksh) - 1);
  int col = ntile * 16 + (lane & 15);
  int k0 = kstep * 32 + ((lane >> 4) << 3);
  const float* s = (k0 < 1024) ? src0 : src1;
  int kk = k0 & 1023;
  bf16x8 v;
#pragma unroll
  for (int j = 0; j < 8; j++) v[j] = f2bf(s[(size_t)(kk + j) * 4096 + col]);
  *(bf16x8*)(dst + (size_t)gid * 8) = v;
}

// ---------------------------------------------------------------------------
// gemm_xw: xz0 = x @ W0, gate-interleaved epilogue [row][unit][gate]
// ---------------------------------------------------------------------------
__global__ __launch_bounds__(256) void gemm_xw(const short* __restrict__ xf,
                                               const short* __restrict__ wf,
                                               short* __restrict__ outz) {
  extern __shared__ char smem[];

  int bid = blockIdx.x;
  int swz = (bid & 7) * 512 + (bid >> 3);
  int bn = swz >> 7;
  int bm = swz & 127;

  const int tid = threadIdx.x, wid = tid >> 6, lane = tid & 63;
  const int wm = wid >> 1, wn = wid & 1;
  f32x4 acc[4][4] = {};

  const short* xbase = xf + (size_t)(bm * 8) * 32 * 512;
  const short* wbase = wf + (size_t)(bn * 8) * 32 * 512;

  auto Abuf = [&](int buf) -> short* { return (short*)(smem + buf * 32768); };
  auto Bbuf = [&](int buf) -> short* { return (short*)(smem + 16384 + buf * 32768); };

  auto stage = [&](int buf, int kt) {
    short* A = Abuf(buf);
    short* B = Bbuf(buf);
#pragma unroll
    for (int i = 0; i < 4; i++) {
      int u = wid + 4 * i;
      int mt = u >> 1, ks = u & 1;
      int gk = kt * 2 + ks;
      g2l16(xbase + (size_t)(mt * 32 + gk) * 512 + lane * 8, A + u * 512);
      g2l16(wbase + (size_t)(mt * 32 + gk) * 512 + lane * 8, B + u * 512);
    }
  };

  stage(0, 0);
  __syncthreads();
  for (int kt = 0; kt < 16; kt++) {
    int buf = kt & 1;
    if (kt < 15) stage(buf ^ 1, kt + 1);
    const short* A = Abuf(buf) + (wm * 4) * 1024;
    const short* B = Bbuf(buf) + (wn * 4) * 1024;
#pragma unroll
    for (int ks = 0; ks < 2; ks++) {
      bf16x8 av[4], bv[4];
#pragma unroll
      for (int i = 0; i < 4; i++) av[i] = *(const bf16x8*)(A + (i * 2 + ks) * 512 + lane * 8);
#pragma unroll
      for (int j = 0; j < 4; j++) bv[j] = *(const bf16x8*)(B + (j * 2 + ks) * 512 + lane * 8);
#pragma unroll
      for (int i = 0; i < 4; i++)
#pragma unroll
        for (int j = 0; j < 4; j++)
          acc[i][j] = __builtin_amdgcn_mfma_f32_16x16x32_bf16(av[i], bv[j], acc[i][j], 0, 0, 0);
    }
    __syncthreads();
  }

  int rb = bm * 128 + wm * 64 + ((lane >> 4) << 2);
  int cb = bn * 128 + wn * 64 + (lane & 15);
#pragma unroll
  for (int i = 0; i < 4; i++)
#pragma unroll
    for (int j = 0; j < 4; j++)
#pragma unroll
      for (int r = 0; r < 4; r++) {
        size_t row = rb + i * 16 + r;
        int col = cb + j * 16;
        outz[row * 4096 + (size_t)(col & 1023) * 4 + (col >> 10)] = f2bf(acc[i][j][r]);
      }
}

// ---------------------------------------------------------------------------
// lstm_persist: wave-autonomous narrow polls, per-wave flags, 1 barrier/mini.
// flags word index: ((L*2+g)*128 + wg)*4 + wave   (L: 0=l0, 1=l1)
// ---------------------------------------------------------------------------
__global__ __launch_bounds__(256, 1) void lstm_persist(
    const short* __restrict__ xz0, const short* __restrict__ u0f,
    const short* __restrict__ w1u1f, const float* __restrict__ b0,
    const float* __restrict__ b1, short* __restrict__ h0ring,
    short* __restrict__ h1ring, unsigned int* __restrict__ flags,
    float* __restrict__ out) {
  extern __shared__ char smem[];
  short* wlds = (short*)smem;                 // weights: 64KB (l0) / 128KB (l1)
  float* red0 = (float*)(smem + 131072);      // 8KB: group0 partials
  float* red1 = (float*)(smem + 139264);      // 8KB: group1 partials

  const int wg = blockIdx.x;
  const int tid = threadIdx.x;
  const int w = tid >> 6;
  const int lane = tid & 63;
  const bool l1 = (wg >= 128);
  const int u0 = (wg & 127) * 8;
  const int KS = l1 ? 64 : 32;
  const int ksh = l1 ? 6 : 5;
  const short* wf = l1 ? w1u1f : u0f;

  // ---- LDS weight fill ----
  {
    int c = lane & 15;
    for (int u = w; u < 2 * KS; u += 4) {
      int tau = u >> ksh;
      int s = u & (KS - 1);
      int gate = tau * 2 + (c >> 3);
      int gc = gate * 1024 + u0 + (c & 7);
      int lanep = (lane & 48) + (gc & 15);
      const short* src = wf + ((size_t)(((gc >> 4) << ksh) + s) * 64 + lanep) * 8;
      g2l16(src, wlds + (tau * KS + s) * 512);
    }
  }
  __syncthreads();

  const int un = lane & 7;
  float bias[4];
  {
    const float* bb = l1 ? b1 : b0;
#pragma unroll
    for (int g4 = 0; g4 < 4; g4++) bias[g4] = bb[g4 * 1024 + u0 + un];
  }

  // narrow polls -------------------------------------------------------------
  auto poll0 = [&](int g, int t) {          // layer0, wave w, group g, step t
    if (t == 0) return;
    const unsigned tgt = (unsigned)t;
    const unsigned lagt = (t >= 8) ? (unsigned)(t - 7) : 0u;
    const unsigned* pp = flags + (unsigned)(g * 128 + w * 32) * 4 + lane * 2;
    const unsigned* pl = flags + (unsigned)((2 + g) * 128 + w * 32 + (lane >> 1)) * 4 + (lane & 1);
    for (int it = 0; it < (1 << 22); ++it) {
      u32x2 ov; unsigned lv;
      asm volatile(
          "global_load_dwordx2 %0, %2, off sc1\n\t"
          "global_load_dword %1, %3, off sc1\n\t"
          "s_waitcnt vmcnt(0)"
          : "=&v"(ov), "=&v"(lv) : "v"(pp), "v"(pl) : "memory");
      if (__all(ov[0] >= tgt && ov[1] >= tgt && lv >= lagt)) break;
      asm volatile("s_sleep 1");
    }
  };
  auto poll1 = [&](int g, int t) {          // layer1, wave w, group g, step t
    unsigned tgt;
    const unsigned* pp;
    if (w < 2) {                            // reads h0(t): l0 flags >= t+1
      tgt = (unsigned)(t + 1);
      pp = flags + (unsigned)(g * 128 + w * 64) * 4 + lane * 4;
    } else {                                // reads h1(t-1): l1 flags >= t
      if (t == 0) return;
      tgt = (unsigned)t;
      pp = flags + (unsigned)((2 + g) * 128 + (w - 2) * 64) * 4 + lane * 4;
    }
    for (int it = 0; it < (1 << 22); ++it) {
      u32x4 v;
      asm volatile(
          "global_load_dwordx4 %0, %1, off sc1\n\t"
          "s_waitcnt vmcnt(0)"
          : "=&v"(v) : "v"(pp) : "memory");
      if (__all(v[0] >= tgt && v[1] >= tgt && v[2] >= tgt && v[3] >= tgt)) break;
      asm volatile("s_sleep 1");
    }
  };

  // gates for this wave's 4 rows of group g (lane<32) -------------------------
  auto gates = [&](const float* rd, s16x4 xv, float& cst, short* hw,
                   bool dump, int g) {
    const int bl = w * 4 + (lane >> 3);     // lane<32 -> bl in [w*4, w*4+4)
    float z[4];
#pragma unroll
    for (int g4 = 0; g4 < 4; g4++) {
      int tau = g4 >> 1;
      int lp = (bl >> 2) * 16 + (g4 & 1) * 8 + un;
      float s = bias[g4] + bf2f(xv[g4]);
#pragma unroll
      for (int w4 = 0; w4 < 4; w4++)
        s += rd[((w4 * 2 + tau) * 64 + lp) * 4 + (bl & 3)];
      z[g4] = s;
    }
    float gi = sigm(z[0]);
    float gf = sigm(z[1]);
    float gg = tanhf(z[2]);
    float go = sigm(z[3]);
    cst = gf * cst + gi * gg;
    float hv = go * tanhf(cst);
    if (dump) {
      int oi = (g * 16 + bl) * 1024 + u0 + un;
      out[oi] = hv;
      out[32768 + oi] = hv;
      out[65536 + oi] = cst;
    }
    st2_sc1(hw + (g * 16 + bl) * 1024 + u0 + un,
            (unsigned)(unsigned short)f2bf(hv));
  };

  auto release = [&](int g, int t) {
    if (lane == 0)
      st4_sc1(flags + (unsigned)(((l1 ? 2 : 0) + g) * 128 + (wg & 127)) * 4 + w,
              (unsigned)(t + 1));
  };

  if (!l1) {
    // ================= layer 0 =================
    float c0 = 0.f, c1 = 0.f;
    auto mini = [&](int g, int t, float& cst) {
      poll0(g, t);
      const short* ap = h0ring + (size_t)((t - 1) & 7) * 32768 +
                        (g * 16 + (lane & 15)) * 1024 + (w << 8) +
                        ((lane >> 4) << 3);
      Frag8 Fa;
      LD8(Fa, ap);
      s16x4 xv = {0, 0, 0, 0};
      if (lane < 32) {
        int bl = w * 4 + (lane >> 3);
        xv = ld8_plain(xz0 +
             (((size_t)((g * 16 + bl) * 512 + t)) * 1024 + u0 + un) * 4);
      }
      SBAR; VM_DRAIN; SBAR;
      f32x4 a0 = {}, a1 = {};
#pragma unroll
      for (int ks = 0; ks < 8; ks++) {
        bf16x8 bt0 = *(const bf16x8*)(wlds + (w * 8 + ks) * 512 + lane * 8);
        bf16x8 bt1 = *(const bf16x8*)(wlds + (32 + w * 8 + ks) * 512 + lane * 8);
        bf16x8 fa = FSEL(Fa, ks);
        a0 = __builtin_amdgcn_mfma_f32_16x16x32_bf16(fa, bt0, a0, 0, 0, 0);
        a1 = __builtin_amdgcn_mfma_f32_16x16x32_bf16(fa, bt1, a1, 0, 0, 0);
      }
      float* rd = g ? red1 : red0;
      *(f32x4*)(rd + ((w * 2 + 0) * 64 + lane) * 4) = a0;
      *(f32x4*)(rd + ((w * 2 + 1) * 64 + lane) * 4) = a1;
      __syncthreads();                     // the only barrier in the mini
      if (lane < 32)
        gates(rd, xv, cst, h0ring + (size_t)(t & 7) * 32768, false, g);
      VM_DRAIN;                            // h-stores acked
      release(g, t);
    };
    for (int t = 0; t < 512; ++t) { mini(0, t, c0); mini(1, t, c1); }
  } else {
    // ================= layer 1 =================
    float c0 = 0.f, c1 = 0.f;
    auto mini = [&](int g, int t, float& cst) {
      poll1(g, t);
      const short* Ab = (w < 2) ? (h0ring + (size_t)(t & 7) * 32768)
                                : (h1ring + (size_t)((t - 1) & 7) * 32768);
      const short* ap = Ab + (g * 16 + (lane & 15)) * 1024 + ((w & 1) << 9) +
                        ((lane >> 4) << 3);
      Frag8 Fa, Fc;
      LD8(Fa, ap);
      LD8(Fc, ap + 256);
      SBAR; VM_DRAIN; SBAR;
      f32x4 a0 = {}, a1 = {};
#pragma unroll
      for (int ks = 0; ks < 8; ks++) {
        bf16x8 bt0 = *(const bf16x8*)(wlds + (w * 16 + ks) * 512 + lane * 8);
        bf16x8 bt1 = *(const bf16x8*)(wlds + (64 + w * 16 + ks) * 512 + lane * 8);
        bf16x8 fa = FSEL(Fa, ks);
        a0 = __builtin_amdgcn_mfma_f32_16x16x32_bf16(fa, bt0, a0, 0, 0, 0);
        a1 = __builtin_amdgcn_mfma_f32_16x16x32_bf16(fa, bt1, a1, 0, 0, 0);
      }
#pragma unroll
      for (int ks = 0; ks < 8; ks++) {
        bf16x8 bt0 = *(const bf16x8*)(wlds + (w * 16 + 8 + ks) * 512 + lane * 8);
        bf16x8 bt1 = *(const bf16x8*)(wlds + (64 + w * 16 + 8 + ks) * 512 + lane * 8);
        bf16x8 fc = FSEL(Fc, ks);
        a0 = __builtin_amdgcn_mfma_f32_16x16x32_bf16(fc, bt0, a0, 0, 0, 0);
        a1 = __builtin_amdgcn_mfma_f32_16x16x32_bf16(fc, bt1, a1, 0, 0, 0);
      }
      float* rd = g ? red1 : red0;
      *(f32x4*)(rd + ((w * 2 + 0) * 64 + lane) * 4) = a0;
      *(f32x4*)(rd + ((w * 2 + 1) * 64 + lane) * 4) = a1;
      __syncthreads();
      if (lane < 32) {
        s16x4 zv = {0, 0, 0, 0};
        gates(rd, zv, cst, h1ring + (size_t)(t & 7) * 32768, t == 511, g);
      }
      VM_DRAIN;
      release(g, t);
    };
    for (int t = 0; t < 512; ++t) { mini(0, t, c0); mini(1, t, c1); }
  }
}

// ---------------------------------------------------------------------------
extern "C" void kernel_launch(void* const* d_in, const int* in_sizes, int n_in,
                              void* d_out, int out_size, void* d_ws, size_t ws_size,
                              hipStream_t stream) {
  const float* x  = (const float*)d_in[0];
  const float* W0 = (const float*)d_in[1];
  const float* U0 = (const float*)d_in[2];
  const float* b0 = (const float*)d_in[3];
  const float* W1 = (const float*)d_in[4];
  const float* U1 = (const float*)d_in[5];
  const float* b1 = (const float*)d_in[6];
  char* ws = (char*)d_ws;
  if (ws_size < WS_TOTAL) return;

  short* xz0p = (short*)(ws + XZ0_OFF);
  short* xfp  = (short*)(ws + XF_OFF);
  short* w0fp = (short*)(ws + W0F_OFF);
  short* u0fp = (short*)(ws + U0F_OFF);
  short* w1fp = (short*)(ws + W1F_OFF);
  short* h0rp = (short*)(ws + H0R_OFF);
  short* h1rp = (short*)(ws + H1R_OFF);
  unsigned int* flagp = (unsigned int*)(ws + FLG_OFF);
  float* outp = (float*)d_out;

  (void)hipFuncSetAttribute((const void*)gemm_xw,
      hipFuncAttributeMaxDynamicSharedMemorySize, 65536);
  (void)hipFuncSetAttribute((const void*)lstm_persist,
      hipFuncAttributeMaxDynamicSharedMemorySize, 147456);

  hipLaunchKernelGGL(pack_x, dim3(8192), dim3(256), 0, stream, x, xfp);
  hipLaunchKernelGGL(pack_w, dim3(2048), dim3(256), 0, stream, W0, W0, 5, w0fp);
  hipLaunchKernelGGL(pack_w, dim3(2048), dim3(256), 0, stream, U0, U0, 5, u0fp);
  hipLaunchKernelGGL(pack_w, dim3(4096), dim3(256), 0, stream, W1, U1, 6, w1fp);
  hipLaunchKernelGGL(gemm_xw, dim3(4096), dim3(256), 65536, stream, xfp, w0fp, xz0p);

  // rings + flags overlay the xf region — zero only after gemm consumed xf
  (void)hipMemsetAsync(ws + H0R_OFF, 0, 524288 + 524288 + 8192, stream);

  const short* xz0c = xz0p;
  const short* u0fc = u0fp;
  const short* w1fc = w1fp;
  void* kargs[9] = {(void*)&xz0c, (void*)&u0fc, (void*)&w1fc,
                    (void*)&b0,   (void*)&b1,
                    (void*)&h0rp, (void*)&h1rp, (void*)&flagp, (void*)&outp};
  (void)hipLaunchCooperativeKernel((const void*)lstm_persist, dim3(256), dim3(256),
                                   kargs, 147456u, stream);
}

// Round 17
// 3930.149 us; speedup vs baseline: 1.9603x; 1.2387x over previous
//
#include <hip/hip_runtime.h>
#include <cstdint>

// ---------------------------------------------------------------------------
// 2-layer LSTM encoder, B=32 T=512 F=H=1024.
// Phase 1: pack x, W0, U0, [W1;U1] into bf16 MFMA-fragment order.
// Phase 2: big GEMM xz0 = x @ W0 (bf16, fp32 accum), GATE-INTERLEAVED output
//          layout [row][unit][gate] so the persist kernel reads one dwordx2.
// Phase 3: persistent cooperative kernel, 256 WGs x 256 threads (4 waves),
//          R5 structure: G=2 serial group-minis, split-K across 4 waves,
//          per-group flags, sc1 LLC protocol. Polls hidden in idle
//          waves (wave2 polls g1(t) during mini0's gates; wave3 polls
//          g0(t+1) during mini1's gates) -> straggler jitter off-path.
//          [Best verified configuration: R11 — resubmitted verbatim.]
// ---------------------------------------------------------------------------

typedef __attribute__((ext_vector_type(8))) short bf16x8;
typedef __attribute__((ext_vector_type(4))) short s16x4;
typedef __attribute__((ext_vector_type(4))) float f32x4;
typedef __attribute__((ext_vector_type(2))) unsigned int u32x2;

// workspace layout (bytes)
#define XZ0_OFF   0ull
#define XF_OFF    134217728ull
#define W0F_OFF   167772160ull
#define U0F_OFF   176160768ull
#define W1F_OFF   184549376ull
#define WS_TOTAL  201326592ull
#define RING_OFF  XF_OFF                 // 8 x 32x1024 bf16 = 524288
#define H1B_OFF   (XF_OFF + 524288ull)   // 2 x 32x1024 bf16 = 131072
#define FLG_OFF   (XF_OFF + 655360ull)   // 512 u32

__device__ __forceinline__ float bf2f(short s) {
  unsigned int u = ((unsigned int)(unsigned short)s) << 16;
  return __builtin_bit_cast(float, u);
}
__device__ __forceinline__ short f2bf(float f) {
  unsigned int u = __builtin_bit_cast(unsigned int, f);
  u = (u + 0x7fffu + ((u >> 16) & 1u)) >> 16;   // RTNE
  return (short)u;
}
__device__ __forceinline__ void g2l16(const void* g, void* l) {
  __builtin_amdgcn_global_load_lds(
      (const __attribute__((address_space(1))) unsigned int*)g,
      (__attribute__((address_space(3))) unsigned int*)l, 16, 0, 0);
}
__device__ __forceinline__ float sigm(float x) { return 1.f / (1.f + __expf(-x)); }

// agent-scope (LLC) access helpers — bypass per-XCD L2 staleness, no fences
__device__ __forceinline__ bf16x8 ld16_sc1(const short* p) {
  bf16x8 r;
  asm volatile("global_load_dwordx4 %0, %1, off sc1" : "=&v"(r) : "v"(p));
  return r;
}
__device__ __forceinline__ void st2_sc1(short* p, unsigned v) {
  asm volatile("global_store_short %0, %1, off sc1" :: "v"(p), "v"(v) : "memory");
}
__device__ __forceinline__ void st4_sc1(unsigned* p, unsigned v) {
  asm volatile("global_store_dword %0, %1, off sc1" :: "v"(p), "v"(v) : "memory");
}
#define VM_DRAIN asm volatile("s_waitcnt vmcnt(0)" ::: "memory")
#define SBAR __builtin_amdgcn_sched_barrier(0)

// ---------------------------------------------------------------------------
// pack_x: x fp32 [16384][1024] -> bf16 fragments [1024 mtiles][32 ksteps][64][8]
// ---------------------------------------------------------------------------
__global__ __launch_bounds__(256) void pack_x(const float* __restrict__ x,
                                              short* __restrict__ dst) {
  int gid = blockIdx.x * 256 + threadIdx.x;
  int lane = gid & 63;
  int unit = gid >> 6;
  int mtile = unit >> 5, kstep = unit & 31;
  int row = mtile * 16 + (lane & 15);
  int k0 = kstep * 32 + ((lane >> 4) << 3);
  const float* s = x + (size_t)row * 1024 + k0;
  bf16x8 v;
#pragma unroll
  for (int j = 0; j < 8; j++) v[j] = f2bf(s[j]);
  *(bf16x8*)(dst + (size_t)gid * 8) = v;
}

// ---------------------------------------------------------------------------
// pack_w: W fp32 [K][4096] -> bf16 fragments [256 ntiles][K/32][64][8]
// ---------------------------------------------------------------------------
__global__ __launch_bounds__(256) void pack_w(const float* __restrict__ src0,
                                              const float* __restrict__ src1,
                                              int ksh, short* __restrict__ dst) {
  int gid = blockIdx.x * 256 + threadIdx.x;
  int lane = gid & 63;
  int unit = gid >> 6;
  int ntile = unit >> ksh;
  int kstep = unit & ((1 << ksh) - 1);
  int col = ntile * 16 + (lane & 15);
  int k0 = kstep * 32 + ((lane >> 4) << 3);
  const float* s = (k0 < 1024) ? src0 : src1;
  int kk = k0 & 1023;
  bf16x8 v;
#pragma unroll
  for (int j = 0; j < 8; j++) v[j] = f2bf(s[(size_t)(kk + j) * 4096 + col]);
  *(bf16x8*)(dst + (size_t)gid * 8) = v;
}

// ---------------------------------------------------------------------------
// gemm_xw: xz0 = x @ W0 (bf16, fp32 accum), gate-interleaved epilogue:
// out index = row*4096 + (col&1023)*4 + (col>>10)   [row][unit][gate]
// ---------------------------------------------------------------------------
__global__ __launch_bounds__(256) void gemm_xw(const short* __restrict__ xf,
                                               const short* __restrict__ wf,
                                               short* __restrict__ outz) {
  extern __shared__ char smem[];

  int bid = blockIdx.x;
  int swz = (bid & 7) * 512 + (bid >> 3);
  int bn = swz >> 7;
  int bm = swz & 127;

  const int tid = threadIdx.x, wid = tid >> 6, lane = tid & 63;
  const int wm = wid >> 1, wn = wid & 1;
  f32x4 acc[4][4] = {};

  const short* xbase = xf + (size_t)(bm * 8) * 32 * 512;
  const short* wbase = wf + (size_t)(bn * 8) * 32 * 512;

  auto Abuf = [&](int buf) -> short* { return (short*)(smem + buf * 32768); };
  auto Bbuf = [&](int buf) -> short* { return (short*)(smem + 16384 + buf * 32768); };

  auto stage = [&](int buf, int kt) {
    short* A = Abuf(buf);
    short* B = Bbuf(buf);
#pragma unroll
    for (int i = 0; i < 4; i++) {
      int u = wid + 4 * i;
      int mt = u >> 1, ks = u & 1;
      int gk = kt * 2 + ks;
      g2l16(xbase + (size_t)(mt * 32 + gk) * 512 + lane * 8, A + u * 512);
      g2l16(wbase + (size_t)(mt * 32 + gk) * 512 + lane * 8, B + u * 512);
    }
  };

  stage(0, 0);
  __syncthreads();
  for (int kt = 0; kt < 16; kt++) {
    int buf = kt & 1;
    if (kt < 15) stage(buf ^ 1, kt + 1);
    const short* A = Abuf(buf) + (wm * 4) * 1024;
    const short* B = Bbuf(buf) + (wn * 4) * 1024;
#pragma unroll
    for (int ks = 0; ks < 2; ks++) {
      bf16x8 av[4], bv[4];
#pragma unroll
      for (int i = 0; i < 4; i++) av[i] = *(const bf16x8*)(A + (i * 2 + ks) * 512 + lane * 8);
#pragma unroll
      for (int j = 0; j < 4; j++) bv[j] = *(const bf16x8*)(B + (j * 2 + ks) * 512 + lane * 8);
#pragma unroll
      for (int i = 0; i < 4; i++)
#pragma unroll
        for (int j = 0; j < 4; j++)
          acc[i][j] = __builtin_amdgcn_mfma_f32_16x16x32_bf16(av[i], bv[j], acc[i][j], 0, 0, 0);
    }
    __syncthreads();
  }

  int rb = bm * 128 + wm * 64 + ((lane >> 4) << 2);
  int cb = bn * 128 + wn * 64 + (lane & 15);
#pragma unroll
  for (int i = 0; i < 4; i++)
#pragma unroll
    for (int j = 0; j < 4; j++)
#pragma unroll
      for (int r = 0; r < 4; r++) {
        size_t row = rb + i * 16 + r;
        int col = cb + j * 16;
        outz[row * 4096 + (size_t)(col & 1023) * 4 + (col >> 10)] = f2bf(acc[i][j][r]);
      }
}

// ---------------------------------------------------------------------------
// lstm_persist: R5 structure + hidden polls.
// flags: [0,128)=l0 g0, [128,256)=l0 g1, [256,384)=l1 g0, [384,512)=l1 g1
// ---------------------------------------------------------------------------
__global__ __launch_bounds__(256, 1) void lstm_persist(
    const short* __restrict__ xz0, const short* __restrict__ u0f,
    const short* __restrict__ w1u1f, const float* __restrict__ b0,
    const float* __restrict__ b1, short* __restrict__ h0ring,
    short* __restrict__ h1buf, unsigned int* __restrict__ flags,
    float* __restrict__ out) {
  extern __shared__ char smem[];
  short* wlds = (short*)smem;                  // weight fragments (64/128KB)
  float* red0 = (float*)(smem + 131072);       // 8KB reduce, group 0
  float* red1 = (float*)(smem + 139264);       // 8KB reduce, group 1

  const int wg = blockIdx.x;
  const int tid = threadIdx.x;
  const int wid = tid >> 6;
  const int lane = tid & 63;
  const bool l1 = (wg >= 128);
  const int u0 = (wg & 127) * 8;
  const int KS = l1 ? 64 : 32;
  const int ksh = l1 ? 6 : 5;
  const short* wf = l1 ? w1u1f : u0f;

  // ---- LDS fill: gather our 32 gate-columns from natural-ntile fragments ----
  {
    int c = lane & 15;
    for (int u = wid; u < 2 * KS; u += 4) {
      int tau = u >> ksh;
      int s = u & (KS - 1);
      int gate = tau * 2 + (c >> 3);
      int gc = gate * 1024 + u0 + (c & 7);
      int lanep = (lane & 48) + (gc & 15);
      const short* src = wf + ((size_t)(((gc >> 4) << ksh) + s) * 64 + lanep) * 8;
      g2l16(src, wlds + (tau * KS + s) * 512);
    }
  }
  __syncthreads();

  const int bl = (tid & 127) >> 3;          // group-local batch row (gates)
  const int uu = tid & 7;
  const int lrow = bl >> 2, reg = bl & 3;
  float bias[4];
  {
    const float* bb = l1 ? b1 : b0;
#pragma unroll
    for (int g = 0; g < 4; g++) bias[g] = bb[g * 1024 + u0 + uu];
  }

  unsigned int* ownbase = flags + (l1 ? 256 : 0);
  unsigned int* othbase = flags + (l1 ? 0 : 256);

  // wave-wide poll of group q's flags (caller guards which wave runs this)
  auto pollq = [&](int q, unsigned own_t, unsigned oth_t) {
    if ((own_t | oth_t) == 0) return;
    const unsigned* po = ownbase + q * 128 + lane * 2;
    const unsigned* pe = othbase + q * 128 + lane * 2;
    for (int it = 0; it < (1 << 22); ++it) {
      u32x2 ov, ev;
      asm volatile(
          "global_load_dwordx2 %0, %2, off sc1\n\t"
          "global_load_dwordx2 %1, %3, off sc1\n\t"
          "s_waitcnt vmcnt(0)"
          : "=&v"(ov), "=&v"(ev)
          : "v"(po), "v"(pe)
          : "memory");
      if (__all(ov[0] >= own_t && ov[1] >= own_t &&
                ev[0] >= oth_t && ev[1] >= oth_t)) break;
      asm volatile("s_sleep 1");
    }
  };

  // gates for one group (tid<128); h-row = g*16+bl
  auto gates1 = [&](const float* rd, s16x4 xv, float& cst, short* hw,
                    bool dump, int g) {
    float z[4];
#pragma unroll
    for (int g4 = 0; g4 < 4; g4++) {
      int tau = g4 >> 1;
      int lp = lrow * 16 + (g4 & 1) * 8 + uu;
      float s = bias[g4] + bf2f(xv[g4]);
#pragma unroll
      for (int w4 = 0; w4 < 4; w4++)
        s += rd[((w4 * 2 + tau) * 64 + lp) * 4 + reg];
      z[g4] = s;
    }
    float gi = sigm(z[0]);
    float gf = sigm(z[1]);
    float gg = tanhf(z[2]);
    float go = sigm(z[3]);
    cst = gf * cst + gi * gg;
    float hv = go * tanhf(cst);
    st2_sc1(hw + (g * 16 + bl) * 1024 + u0 + uu,
            (unsigned)(unsigned short)f2bf(hv));
    if (dump) {
      int oi = (g * 16 + bl) * 1024 + u0 + uu;
      out[oi] = hv;
      out[32768 + oi] = hv;
      out[65536 + oi] = cst;
    }
  };

  if (!l1) {
    // ---------------- layer 0: 512 steps, h0 ring depth 8 -------------------
    float c0 = 0.f, c1 = 0.f;
    auto mini = [&](int g, int t, float& cst) {
      // A loads (poll for this mini confirmed before last barrier)
      const short* ap = h0ring + (size_t)((t - 1) & 7) * 32768 +
                        (g * 16 + (lane & 15)) * 1024 + (wid << 8) +
                        ((lane >> 4) << 3);
      bf16x8 a[8];
#pragma unroll
      for (int ks = 0; ks < 8; ks++) a[ks] = ld16_sc1(ap + ks * 32);
      s16x4 xv = {0, 0, 0, 0};
      if (tid < 128)
        xv = *(const s16x4*)(xz0 +
              ((size_t)((g * 16 + bl) * 512 + t) * 1024 + u0 + uu) * 4);
      SBAR; VM_DRAIN; SBAR;
      f32x4 acc[2] = {};
#pragma unroll
      for (int ks = 0; ks < 8; ks++) {
        bf16x8 bt0 = *(const bf16x8*)(wlds + (wid * 8 + ks) * 512 + lane * 8);
        bf16x8 bt1 = *(const bf16x8*)(wlds + (32 + wid * 8 + ks) * 512 + lane * 8);
        acc[0] = __builtin_amdgcn_mfma_f32_16x16x32_bf16(a[ks], bt0, acc[0], 0, 0, 0);
        acc[1] = __builtin_amdgcn_mfma_f32_16x16x32_bf16(a[ks], bt1, acc[1], 0, 0, 0);
      }
      float* rd = g ? red1 : red0;
#pragma unroll
      for (int tau = 0; tau < 2; tau++)
        *(f32x4*)(rd + ((wid * 2 + tau) * 64 + lane) * 4) = acc[tau];
      __syncthreads();
      if (tid < 128) {
        gates1(rd, xv, cst, h0ring + (size_t)(t & 7) * 32768, false, g);
      } else if (wid == 2 && g == 0) {
        // hide poll for mini1(t): own g1 >= t, l1-consumed lag
        pollq(1, (unsigned)t, (t >= 8) ? (unsigned)(t - 7) : 0u);
      } else if (wid == 3 && g == 1 && t < 511) {
        // hide poll for mini0(t+1)
        pollq(0, (unsigned)(t + 1), (t + 1 >= 8) ? (unsigned)(t - 6) : 0u);
      }
      VM_DRAIN;
      __syncthreads();
      if (tid == 0) st4_sc1(ownbase + g * 128 + (wg & 127), (unsigned)(t + 1));
    };
    for (int t = 0; t < 512; ++t) { mini(0, t, c0); mini(1, t, c1); }
  } else {
    // ---------------- layer 1: 512 steps, h0 ring + h1 double buffer --------
    float c0 = 0.f, c1 = 0.f;
    if (wid == 3) pollq(0, 0u, 1u);      // prologue: mini0(0) needs l0 g0 >= 1
    __syncthreads();
    auto mini = [&](int g, int t, float& cst) {
      const short* Ab = (wid < 2) ? (h0ring + (size_t)(t & 7) * 32768)
                                  : (h1buf + (size_t)((t - 1) & 1) * 32768);
      const short* ap = Ab + (g * 16 + (lane & 15)) * 1024 + ((wid & 1) << 9) +
                        ((lane >> 4) << 3);
      bf16x8 a[2][8];
#pragma unroll
      for (int half = 0; half < 2; half++)
#pragma unroll
        for (int ks = 0; ks < 8; ks++)
          a[half][ks] = ld16_sc1(ap + half * 256 + ks * 32);
      SBAR; VM_DRAIN; SBAR;
      f32x4 acc[2] = {};
#pragma unroll
      for (int half = 0; half < 2; half++) {
        const int rb = wid * 16 + half * 8;
#pragma unroll
        for (int ks = 0; ks < 8; ks++) {
          bf16x8 bt0 = *(const bf16x8*)(wlds + (rb + ks) * 512 + lane * 8);
          bf16x8 bt1 = *(const bf16x8*)(wlds + (64 + rb + ks) * 512 + lane * 8);
          acc[0] = __builtin_amdgcn_mfma_f32_16x16x32_bf16(a[half][ks], bt0, acc[0], 0, 0, 0);
          acc[1] = __builtin_amdgcn_mfma_f32_16x16x32_bf16(a[half][ks], bt1, acc[1], 0, 0, 0);
        }
      }
      float* rd = g ? red1 : red0;
#pragma unroll
      for (int tau = 0; tau < 2; tau++)
        *(f32x4*)(rd + ((wid * 2 + tau) * 64 + lane) * 4) = acc[tau];
      __syncthreads();
      if (tid < 128) {
        s16x4 zv = {0, 0, 0, 0};
        gates1(rd, zv, cst, h1buf + (size_t)(t & 1) * 32768, t == 511, g);
      } else if (wid == 2 && g == 0) {
        // hide poll for mini1(t): own g1 >= t, l0 g1 >= t+1
        pollq(1, (unsigned)t, (unsigned)(t + 1));
      } else if (wid == 3 && g == 1 && t < 511) {
        // hide poll for mini0(t+1): own g0 >= t+1, l0 g0 >= t+2
        pollq(0, (unsigned)(t + 1), (unsigned)(t + 2));
      }
      VM_DRAIN;
      __syncthreads();
      if (tid == 0) st4_sc1(ownbase + g * 128 + (wg & 127), (unsigned)(t + 1));
    };
    for (int t = 0; t < 512; ++t) { mini(0, t, c0); mini(1, t, c1); }
  }
}

// ---------------------------------------------------------------------------
extern "C" void kernel_launch(void* const* d_in, const int* in_sizes, int n_in,
                              void* d_out, int out_size, void* d_ws, size_t ws_size,
                              hipStream_t stream) {
  const float* x  = (const float*)d_in[0];
  const float* W0 = (const float*)d_in[1];
  const float* U0 = (const float*)d_in[2];
  const float* b0 = (const float*)d_in[3];
  const float* W1 = (const float*)d_in[4];
  const float* U1 = (const float*)d_in[5];
  const float* b1 = (const float*)d_in[6];
  char* ws = (char*)d_ws;
  if (ws_size < WS_TOTAL) return;  // loud failure: no output written

  short* xz0p = (short*)(ws + XZ0_OFF);
  short* xfp  = (short*)(ws + XF_OFF);
  short* w0fp = (short*)(ws + W0F_OFF);
  short* u0fp = (short*)(ws + U0F_OFF);
  short* w1fp = (short*)(ws + W1F_OFF);
  short* ringp = (short*)(ws + RING_OFF);
  short* h1p   = (short*)(ws + H1B_OFF);
  unsigned int* flagp = (unsigned int*)(ws + FLG_OFF);
  float* outp = (float*)d_out;

  (void)hipFuncSetAttribute((const void*)gemm_xw,
      hipFuncAttributeMaxDynamicSharedMemorySize, 65536);
  (void)hipFuncSetAttribute((const void*)lstm_persist,
      hipFuncAttributeMaxDynamicSharedMemorySize, 147456);

  hipLaunchKernelGGL(pack_x, dim3(8192), dim3(256), 0, stream, x, xfp);
  hipLaunchKernelGGL(pack_w, dim3(2048), dim3(256), 0, stream, W0, W0, 5, w0fp);
  hipLaunchKernelGGL(pack_w, dim3(2048), dim3(256), 0, stream, U0, U0, 5, u0fp);
  hipLaunchKernelGGL(pack_w, dim3(4096), dim3(256), 0, stream, W1, U1, 6, w1fp);
  hipLaunchKernelGGL(gemm_xw, dim3(4096), dim3(256), 65536, stream, xfp, w0fp, xz0p);

  // ring/h1/flags overlay the xf region — zero them only after gemm consumed xf
  (void)hipMemsetAsync(ws + RING_OFF, 0, 524288 + 131072 + 4096, stream);

  const short* xz0c = xz0p;
  const short* u0fc = u0fp;
  const short* w1fc = w1fp;
  void* kargs[9] = {(void*)&xz0c, (void*)&u0fc, (void*)&w1fc,
                    (void*)&b0,   (void*)&b1,
                    (void*)&ringp, (void*)&h1p, (void*)&flagp, (void*)&outp};
  (void)hipLaunchCooperativeKernel((const void*)lstm_persist, dim3(256), dim3(256),
                                   kargs, 147456u, stream);
}